// Round 4
// baseline (479.893 us; speedup 1.0000x reference)
//
#include <hip/hip_runtime.h>
#include <hip/hip_bf16.h>
#include <math.h>

// N=768, D=32, C=10, H=256. Pairs = 768^2. MLP 149->256->256->1.
// feat@W1+b1 = |zi-zj|@W1[64:96] + (zi*zj)@W1[96:128] + R[i] + C[j]
//   R[i] = z[i]@W1[0:32] + p[i]@W1[128:138]
//   C[j] = z[j]@W1[32:64] + p[j]@W1[138:148] + b1 + hom*W1[148]
// Layer-1 K = 128: [0:64) feat(abs|prod), [64:72) R one-hot, [72:88) C one-hot,
// [88:96) R residual, [96:112) C residual, [112:128) zero-pad.
// Block = 128 pairs (8 i x 16 j), 512 thr, 8 waves (2m x 4n), 4 n/k-chunks of 64.

typedef _Float16 f16x8 __attribute__((ext_vector_type(8)));
typedef float f32x4 __attribute__((ext_vector_type(4)));

#define MFMA16(a, b, c) __builtin_amdgcn_mfma_f32_16x16x32_f16(a, b, c, 0, 0, 0)

#define NN 768
#define HH 256

// ---------------- prep: R/C transposed panels ----------------
// grid (12,4), 256 thr. Tile: 64 i x 64 n. Emits RhT/ChT/R2hT/C2hT [256 n][768 i] f16.
__global__ void prep_rc(const float* __restrict__ z, const float* __restrict__ lp,
                        const float* __restrict__ hom, const float* __restrict__ W1,
                        const float* __restrict__ b1,
                        _Float16* __restrict__ RhT, _Float16* __restrict__ ChT,
                        _Float16* __restrict__ R2hT, _Float16* __restrict__ C2hT) {
  __shared__ float rt[64][65];
  __shared__ float ct[64][65];
  const int t = threadIdx.x;
  const int ib = blockIdx.x * 64, nb = blockIdx.y * 64;
  {
    const int il = t >> 2;          // 0..63
    const int ns = (t & 3) * 16;    // 0/16/32/48
    const int ig = ib + il;
    float racc[16], cacc[16];
    #pragma unroll
    for (int u = 0; u < 16; ++u) { racc[u] = 0.f; cacc[u] = 0.f; }
    for (int d = 0; d < 32; ++d) {
      float zr = z[ig * 32 + d];
      const float* wr = W1 + d * HH + nb + ns;
      const float* wc = W1 + (32 + d) * HH + nb + ns;
      #pragma unroll
      for (int u = 0; u < 16; ++u) { racc[u] += zr * wr[u]; cacc[u] += zr * wc[u]; }
    }
    #pragma unroll
    for (int k = 0; k < 10; ++k) {
      float pv = lp[ig * 10 + k];
      const float* wr = W1 + (128 + k) * HH + nb + ns;
      const float* wc = W1 + (138 + k) * HH + nb + ns;
      #pragma unroll
      for (int u = 0; u < 16; ++u) { racc[u] += pv * wr[u]; cacc[u] += pv * wc[u]; }
    }
    float hv = hom[0];
    #pragma unroll
    for (int u = 0; u < 16; ++u)
      cacc[u] += b1[nb + ns + u] + hv * W1[148 * HH + nb + ns + u];
    #pragma unroll
    for (int u = 0; u < 16; ++u) { rt[il][ns + u] = racc[u]; ct[il][ns + u] = cacc[u]; }
  }
  __syncthreads();
  {
    const int nl = t >> 2;          // 0..63
    const int is = (t & 3) * 16;    // 0/16/32/48
    _Float16 o1[16], o2[16], o3[16], o4[16];
    #pragma unroll
    for (int u = 0; u < 16; ++u) {
      float r = rt[is + u][nl];
      _Float16 rh = (_Float16)r;
      o1[u] = rh; o2[u] = (_Float16)(r - (float)rh);
      float c = ct[is + u][nl];
      _Float16 chv = (_Float16)c;
      o3[u] = chv; o4[u] = (_Float16)(c - (float)chv);
    }
    const long base = (long)(nb + nl) * NN + ib + is;
    *(int4*)&RhT[base]      = *(int4*)&o1[0];  *(int4*)&RhT[base + 8]  = *(int4*)&o1[8];
    *(int4*)&R2hT[base]     = *(int4*)&o2[0];  *(int4*)&R2hT[base + 8] = *(int4*)&o2[8];
    *(int4*)&ChT[base]      = *(int4*)&o3[0];  *(int4*)&ChT[base + 8]  = *(int4*)&o3[8];
    *(int4*)&C2hT[base]     = *(int4*)&o4[0];  *(int4*)&C2hT[base + 8] = *(int4*)&o4[8];
  }
}

// Wm[n][kk]: kk<32 -> W1[64+kk][n] (abs), kk>=32 -> W1[96+kk-32][n] (prod). f16.
// W2t[n][k] = W2[k][n]. f16.
__global__ void prep_w(const float* __restrict__ W1, const float* __restrict__ W2,
                       _Float16* __restrict__ Wm, _Float16* __restrict__ W2t) {
  int idx = blockIdx.x * 256 + threadIdx.x;  // grid 320
  if (idx < 256 * 64) {
    int n = idx >> 6, kk = idx & 63;
    float v = (kk < 32) ? W1[(64 + kk) * HH + n] : W1[(96 + (kk - 32)) * HH + n];
    Wm[n * 64 + kk] = (_Float16)v;
  } else {
    int q = idx - 256 * 64;
    int n = q >> 8, k = q & 255;
    W2t[n * 256 + k] = (_Float16)W2[k * 256 + n];
  }
}

// ---------------- fused MLP ----------------
// LDS: l1b [64 n][256B] 16KB | w2c [256 n][128B] 32KB | h1c [128 p][128B] 16KB.
// red (epilogue) aliases l1b. All panels XOR-swizzled by (row&7)<<4.
__global__ __launch_bounds__(512, 2) void fused_mlp(
    const float* __restrict__ z,
    const _Float16* __restrict__ RhT, const _Float16* __restrict__ ChT,
    const _Float16* __restrict__ R2hT, const _Float16* __restrict__ C2hT,
    const _Float16* __restrict__ Wm, const _Float16* __restrict__ W2t,
    const float* __restrict__ b2, const float* __restrict__ W3,
    const float* __restrict__ b3, float* __restrict__ out) {
  __shared__ __align__(16) unsigned char lds[65536];
  unsigned char* l1b = lds;            // [64][256B]
  unsigned char* w2c = lds + 16384;    // [256][128B]
  unsigned char* h1c = lds + 49152;    // [128][128B]
  float* red = (float*)lds;            // [128][4] (epilogue, aliases dead l1b)

  const int tid = threadIdx.x;
  const int wid = tid >> 6;
  const int l = tid & 63;
  const int lr = l & 15;
  const int lg = l >> 4;
  const int wm = wid >> 2;      // 0..1  (m band: 64 pairs)
  const int wn = wid & 3;       // 0..3  (n slice: 64 cols)
  const int bi = blockIdx.x;    // 0..95  (8 i's)
  const int bj = blockIdx.y;    // 0..47  (16 j's)

  // ---- per-lane preloads ----
  float b2v[4], w3v[4];
  #pragma unroll
  for (int nt = 0; nt < 4; ++nt) {
    b2v[nt] = b2[wn * 64 + nt * 16 + lr];
    w3v[nt] = W3[wn * 64 + nt * 16 + lr];
  }
  const float b3v = b3[0];

  // ---- build layer-1 A fragments (pair rows: p = wm*64 + mt*16 + lr; il=wm*4+mt, jl=lr) ----
  f16x8 a0[4], a1[4], a2[4], a3;
  {
    const float4* zj4 = (const float4*)(z + (bj * 16 + lr) * 32 + lg * 8);
    float4 zja = zj4[0], zjb = zj4[1];
    float zj[8] = {zja.x, zja.y, zja.z, zja.w, zjb.x, zjb.y, zjb.z, zjb.w};
    #pragma unroll
    for (int mt = 0; mt < 4; ++mt) {
      const int il = wm * 4 + mt;
      const float* zip = z + (bi * 8 + il) * 32 + lg * 8;
      #pragma unroll
      for (int t = 0; t < 8; ++t) {
        float x = zip[t], y = zj[t];
        a0[mt][t] = (_Float16)fabsf(x - y);
        a1[mt][t] = (_Float16)(x * y);
      }
      #pragma unroll
      for (int t = 0; t < 8; ++t) {
        int k = 64 + lg * 8 + t;
        float v = (k < 72) ? (float)(k - 64 == il)
                : (k < 88) ? (float)(k - 72 == lr)
                           : (float)(k - 88 == il);
        a2[mt][t] = (_Float16)v;
      }
    }
    #pragma unroll
    for (int t = 0; t < 8; ++t) {
      int k = 96 + lg * 8 + t;
      a3[t] = (_Float16)(float)(k < 112 && (k - 96) == lr);
    }
  }

  // ---- staging helpers (manually inlined) ----
  // L1B chunk c: 64 rows x 16 chunks of 16B. row n (global col c*64+nl):
  //   ch 0-7: Wm row; ch 8: RhT; ch 9-10: ChT; ch 11: R2hT; ch 12-13: C2hT; ch 14-15: zero.
  int4 l1v[2];
  int4 w2v[4];

  #define L1B_LOAD(c)                                                              \
    _Pragma("unroll") for (int s = 0; s < 2; ++s) {                                \
      int q = tid + 512 * s;                                                       \
      int nl = q >> 4, ch = q & 15;                                                \
      int ng = (c) * 64 + nl;                                                      \
      int4 v;                                                                      \
      if (ch < 8)       v = *(const int4*)(Wm + ng * 64 + ch * 8);                 \
      else if (ch == 8) v = *(const int4*)(RhT + (long)ng * NN + bi * 8);          \
      else if (ch == 9) v = *(const int4*)(ChT + (long)ng * NN + bj * 16);         \
      else if (ch == 10) v = *(const int4*)(ChT + (long)ng * NN + bj * 16 + 8);    \
      else if (ch == 11) v = *(const int4*)(R2hT + (long)ng * NN + bi * 8);        \
      else if (ch == 12) v = *(const int4*)(C2hT + (long)ng * NN + bj * 16);       \
      else if (ch == 13) v = *(const int4*)(C2hT + (long)ng * NN + bj * 16 + 8);   \
      else               v = (int4){0, 0, 0, 0};                                   \
      l1v[s] = v;                                                                  \
    }
  #define L1B_WRITE()                                                              \
    _Pragma("unroll") for (int s = 0; s < 2; ++s) {                                \
      int q = tid + 512 * s;                                                       \
      int nl = q >> 4, ch = q & 15;                                                \
      *(int4*)(l1b + nl * 256 + ((ch * 16) ^ ((nl & 7) << 4))) = l1v[s];           \
    }
  #define W2C_LOAD(c)                                                              \
    _Pragma("unroll") for (int s = 0; s < 4; ++s) {                                \
      int q = tid + 512 * s;                                                       \
      int n = q >> 3, ch = q & 7;                                                  \
      w2v[s] = *(const int4*)(W2t + n * 256 + (c) * 64 + ch * 8);                  \
    }
  #define W2C_WRITE()                                                              \
    _Pragma("unroll") for (int s = 0; s < 4; ++s) {                                \
      int q = tid + 512 * s;                                                       \
      int n = q >> 3, ch = q & 7;                                                  \
      *(int4*)(w2c + n * 128 + ((ch * 16) ^ ((n & 7) << 4))) = w2v[s];             \
    }

  // ---- prologue: stage chunk 0 ----
  L1B_LOAD(0); W2C_LOAD(0);
  L1B_WRITE(); W2C_WRITE();
  __syncthreads();

  f32x4 acc2[4][4];
  #pragma unroll
  for (int mt = 0; mt < 4; ++mt)
    #pragma unroll
    for (int nt = 0; nt < 4; ++nt) acc2[mt][nt] = (f32x4){0.f, 0.f, 0.f, 0.f};

  const int nlb = wn * 16 + lr;   // layer-1 B col (local), layer-1 D col
  for (int c = 0; c < 4; ++c) {
    // ---- layer-1 chunk: h1[wm band 64 rows][wn 16 cols] ----
    f32x4 acc1[4];
    #pragma unroll
    for (int mt = 0; mt < 4; ++mt) acc1[mt] = (f32x4){0.f, 0.f, 0.f, 0.f};
    #pragma unroll
    for (int ks = 0; ks < 4; ++ks) {
      f16x8 b = *(const f16x8*)(l1b + nlb * 256 + ((ks * 64 + lg * 16) ^ ((nlb & 7) << 4)));
      #pragma unroll
      for (int mt = 0; mt < 4; ++mt) {
        f16x8 a = (ks == 0) ? a0[mt] : (ks == 1) ? a1[mt] : (ks == 2) ? a2[mt] : a3;
        acc1[mt] = MFMA16(a, b, acc1[mt]);
      }
    }
    // pack (relu, f16) -> h1c [128 rows][64 k]
    #pragma unroll
    for (int mt = 0; mt < 4; ++mt) {
      #pragma unroll
      for (int r = 0; r < 4; ++r) {
        int row = wm * 64 + mt * 16 + 4 * lg + r;
        float v = acc1[mt][r];
        v = v > 0.f ? v : 0.f;
        *(_Float16*)(h1c + row * 128 + ((nlb * 2) ^ ((row & 7) << 4))) = (_Float16)v;
      }
    }
    // issue next chunk's global loads (latency hidden under compute)
    if (c < 3) { L1B_LOAD(c + 1); W2C_LOAD(c + 1); }
    __syncthreads();                  // h1c visible; l1b[c] reads done
    if (c < 3) { L1B_WRITE(); }
    // ---- layer-2 partial: acc2 += h1c @ W2[kchunk] ----
    #pragma unroll
    for (int ks = 0; ks < 2; ++ks) {
      f16x8 af[4];
      #pragma unroll
      for (int mt = 0; mt < 4; ++mt) {
        int row = wm * 64 + mt * 16 + lr;
        af[mt] = *(const f16x8*)(h1c + row * 128 + ((ks * 64 + lg * 16) ^ ((row & 7) << 4)));
      }
      #pragma unroll
      for (int nt = 0; nt < 4; ++nt) {
        int rw = wn * 64 + nt * 16 + lr;
        f16x8 bf = *(const f16x8*)(w2c + rw * 128 + ((ks * 64 + lg * 16) ^ ((rw & 7) << 4)));
        #pragma unroll
        for (int mt = 0; mt < 4; ++mt) acc2[mt][nt] = MFMA16(af[mt], bf, acc2[mt][nt]);
      }
    }
    __syncthreads();                  // w2c[c]/h1c reads done; l1b[c+1] visible
    if (c < 3) { W2C_WRITE(); }
  }

  // ---- epilogue: +b2, relu, dot W3 (fp32), cross-wave reduce, sigmoid ----
  #pragma unroll
  for (int mt = 0; mt < 4; ++mt) {
    #pragma unroll
    for (int r = 0; r < 4; ++r) {
      float sum = 0.f;
      #pragma unroll
      for (int nt = 0; nt < 4; ++nt) {
        float h2 = acc2[mt][nt][r] + b2v[nt];
        h2 = h2 > 0.f ? h2 : 0.f;
        sum += h2 * w3v[nt];
      }
      sum += __shfl_xor(sum, 1);
      sum += __shfl_xor(sum, 2);
      sum += __shfl_xor(sum, 4);
      sum += __shfl_xor(sum, 8);
      if (lr == 0) {
        int row = wm * 64 + mt * 16 + 4 * lg + r;
        red[row * 4 + wn] = sum;     // red aliases l1b (dead after last chunk)
      }
    }
  }
  __syncthreads();
  if (tid < 128) {
    int row = tid;
    float logit = red[row * 4 + 0] + red[row * 4 + 1] + red[row * 4 + 2] + red[row * 4 + 3] + b3v;
    float prob = 1.f / (1.f + expf(-logit));
    out[(bi * 8 + (row >> 4)) * NN + bj * 16 + (row & 15)] = prob;
  }
}

// ---------------- symmetrize in-place: out = 0.5*(P + P^T), zero diag ----------------
__global__ void sym_kernel(float* __restrict__ out) {
  int idx = blockIdx.x * 256 + threadIdx.x;
  if (idx >= NN * NN) return;
  int i = idx / NN, j = idx % NN;
  if (i < j) {
    float a = out[i * NN + j], b = out[j * NN + i];
    float v = 0.5f * (a + b);
    out[i * NN + j] = v;
    out[j * NN + i] = v;
  } else if (i == j) {
    out[idx] = 0.f;
  }
}

extern "C" void kernel_launch(void* const* d_in, const int* in_sizes, int n_in,
                              void* d_out, int out_size, void* d_ws, size_t ws_size,
                              hipStream_t stream) {
  const float* z   = (const float*)d_in[0];
  const float* lp  = (const float*)d_in[1];
  const float* hom = (const float*)d_in[2];
  const float* W1  = (const float*)d_in[3];
  const float* b1  = (const float*)d_in[4];
  const float* W2  = (const float*)d_in[5];
  const float* b2  = (const float*)d_in[6];
  const float* W3  = (const float*)d_in[7];
  const float* b3  = (const float*)d_in[8];
  float* out = (float*)d_out;

  char* ws = (char*)d_ws;
  _Float16* RhT  = (_Float16*)(ws);                  // 256*768*2 = 393216 each
  _Float16* ChT  = (_Float16*)(ws + 393216);
  _Float16* R2hT = (_Float16*)(ws + 786432);
  _Float16* C2hT = (_Float16*)(ws + 1179648);
  _Float16* Wm   = (_Float16*)(ws + 1572864);        // 256*64*2 = 32768
  _Float16* W2t  = (_Float16*)(ws + 1605632);        // 256*256*2 = 131072 -> end 1736704

  prep_rc<<<dim3(12, 4), 256, 0, stream>>>(z, lp, hom, W1, b1, RhT, ChT, R2hT, C2hT);
  prep_w<<<320, 256, 0, stream>>>(W1, W2, Wm, W2t);
  fused_mlp<<<dim3(96, 48), 512, 0, stream>>>(z, RhT, ChT, R2hT, C2hT, Wm, W2t, b2, W3, b3, out);
  sym_kernel<<<2304, 256, 0, stream>>>(out);
}

// Round 5
// 449.275 us; speedup vs baseline: 1.0681x; 1.0681x over previous
//
#include <hip/hip_runtime.h>
#include <hip/hip_bf16.h>
#include <math.h>

// N=768, D=32, C=10, H=256. Pairs = 768^2. MLP 149->256->256->1.
// feat@W1+b1 = |zi-zj|@W1[64:96] + (zi*zj)@W1[96:128] + R[i] + C[j]
//   R[i] = z[i]@W1[0:32] + p[i]@W1[128:138]
//   C[j] = z[j]@W1[32:64] + p[j]@W1[138:148] + b1 + hom*W1[148]
// Layer-1 K = 128: [0:64) feat(abs|prod), [64:72) R one-hot, [72:88) C one-hot,
// [88:96) R residual, [96:112) C residual, [112:128) zero-pad.
// Block = 128 pairs (8 i x 16 j), 512 thr, 8 waves (2m x 4n), 4 n/k-chunks of 64.
// Layer 1 computed TRANSPOSED (D[hidden][pair]) so each lane's D fragment holds
// 4 consecutive hidden values of one pair -> b64 h1 pack instead of 16x b16.

typedef _Float16 f16x8 __attribute__((ext_vector_type(8)));
typedef _Float16 f16x4 __attribute__((ext_vector_type(4)));
typedef float f32x4 __attribute__((ext_vector_type(4)));

#define MFMA16(a, b, c) __builtin_amdgcn_mfma_f32_16x16x32_f16(a, b, c, 0, 0, 0)

#define NN 768
#define HH 256

// ---------------- merged prep ----------------
// blocks [0,48): R/C transposed panels. Tile 64 i x 64 n -> RhT/ChT/R2hT/C2hT [256][768] f16.
// blocks [48,368): Wm[n][kk] f16 (kk<32: W1[64+kk][n]; else W1[96+kk-32][n]); W2t[n][k]=W2[k][n] f16.
__global__ void prep_all(const float* __restrict__ z, const float* __restrict__ lp,
                         const float* __restrict__ hom, const float* __restrict__ W1,
                         const float* __restrict__ b1, const float* __restrict__ W2,
                         _Float16* __restrict__ RhT, _Float16* __restrict__ ChT,
                         _Float16* __restrict__ R2hT, _Float16* __restrict__ C2hT,
                         _Float16* __restrict__ Wm, _Float16* __restrict__ W2t) {
  __shared__ float rt[64][65];
  __shared__ float ct[64][65];
  const int t = threadIdx.x;
  if (blockIdx.x < 48) {
    const int ib = (blockIdx.x % 12) * 64, nb = (blockIdx.x / 12) * 64;
    {
      const int il = t >> 2;          // 0..63
      const int ns = (t & 3) * 16;    // 0/16/32/48
      const int ig = ib + il;
      float racc[16], cacc[16];
      #pragma unroll
      for (int u = 0; u < 16; ++u) { racc[u] = 0.f; cacc[u] = 0.f; }
      for (int d = 0; d < 32; ++d) {
        float zr = z[ig * 32 + d];
        const float* wr = W1 + d * HH + nb + ns;
        const float* wc = W1 + (32 + d) * HH + nb + ns;
        #pragma unroll
        for (int u = 0; u < 16; ++u) { racc[u] += zr * wr[u]; cacc[u] += zr * wc[u]; }
      }
      #pragma unroll
      for (int k = 0; k < 10; ++k) {
        float pv = lp[ig * 10 + k];
        const float* wr = W1 + (128 + k) * HH + nb + ns;
        const float* wc = W1 + (138 + k) * HH + nb + ns;
        #pragma unroll
        for (int u = 0; u < 16; ++u) { racc[u] += pv * wr[u]; cacc[u] += pv * wc[u]; }
      }
      float hv = hom[0];
      #pragma unroll
      for (int u = 0; u < 16; ++u)
        cacc[u] += b1[nb + ns + u] + hv * W1[148 * HH + nb + ns + u];
      #pragma unroll
      for (int u = 0; u < 16; ++u) { rt[il][ns + u] = racc[u]; ct[il][ns + u] = cacc[u]; }
    }
    __syncthreads();
    {
      const int nl = t >> 2;          // 0..63
      const int is = (t & 3) * 16;    // 0/16/32/48
      _Float16 o1[16], o2[16], o3[16], o4[16];
      #pragma unroll
      for (int u = 0; u < 16; ++u) {
        float r = rt[is + u][nl];
        _Float16 rh = (_Float16)r;
        o1[u] = rh; o2[u] = (_Float16)(r - (float)rh);
        float c = ct[is + u][nl];
        _Float16 chv = (_Float16)c;
        o3[u] = chv; o4[u] = (_Float16)(c - (float)chv);
      }
      const long base = (long)(nb + nl) * NN + ib + is;
      *(int4*)&RhT[base]  = *(int4*)&o1[0];  *(int4*)&RhT[base + 8]  = *(int4*)&o1[8];
      *(int4*)&R2hT[base] = *(int4*)&o2[0];  *(int4*)&R2hT[base + 8] = *(int4*)&o2[8];
      *(int4*)&ChT[base]  = *(int4*)&o3[0];  *(int4*)&ChT[base + 8]  = *(int4*)&o3[8];
      *(int4*)&C2hT[base] = *(int4*)&o4[0];  *(int4*)&C2hT[base + 8] = *(int4*)&o4[8];
    }
  } else {
    int idx = (blockIdx.x - 48) * 256 + t;
    if (idx < 256 * 64) {
      int n = idx >> 6, kk = idx & 63;
      float v = (kk < 32) ? W1[(64 + kk) * HH + n] : W1[(96 + (kk - 32)) * HH + n];
      Wm[n * 64 + kk] = (_Float16)v;
    } else {
      int q = idx - 256 * 64;
      int n = q >> 8, k = q & 255;
      W2t[n * 256 + k] = (_Float16)W2[k * 256 + n];
    }
  }
}

// ---------------- fused MLP ----------------
// LDS: l1b [64 n][256B] 16KB | w2c [256 n][128B] 32KB | h1c [128 p][128B] 16KB.
// red (epilogue) aliases l1b. Panels XOR-swizzled by (row&7)<<4.
__global__ __launch_bounds__(512, 1) void fused_mlp(
    const float* __restrict__ z,
    const _Float16* __restrict__ RhT, const _Float16* __restrict__ ChT,
    const _Float16* __restrict__ R2hT, const _Float16* __restrict__ C2hT,
    const _Float16* __restrict__ Wm, const _Float16* __restrict__ W2t,
    const float* __restrict__ b2, const float* __restrict__ W3,
    const float* __restrict__ b3, float* __restrict__ out) {
  __shared__ __align__(16) unsigned char lds[65536];
  unsigned char* l1b = lds;            // [64][256B]
  unsigned char* w2c = lds + 16384;    // [256][128B]
  unsigned char* h1c = lds + 49152;    // [128][128B]
  float* red = (float*)lds;            // [128][4] epilogue, aliases dead l1b

  const int tid = threadIdx.x;
  const int wid = tid >> 6;
  const int l = tid & 63;
  const int lr = l & 15;
  const int lg = l >> 4;
  const int wm = wid >> 2;      // 0..1  (m band: 64 pairs)
  const int wn = wid & 3;       // 0..3  (n slice: 64 cols)
  const int bi = blockIdx.x;    // 0..95  (8 i's)
  const int bj = blockIdx.y;    // 0..47  (16 j's)

  // ---- per-lane preloads ----
  float b2v[4], w3v[4];
  #pragma unroll
  for (int nt = 0; nt < 4; ++nt) {
    b2v[nt] = b2[wn * 64 + nt * 16 + lr];
    w3v[nt] = W3[wn * 64 + nt * 16 + lr];
  }
  const float b3v = b3[0];

  // ---- layer-1 feature fragments (valid as MFMA B-operand: lane holds
  //      B[k = lg*8+t][paircol = lr] for pair-tile mt; pair = wm*64+mt*16+lr) ----
  f16x8 a0[4], a1[4], a2[4], a3;
  {
    const float4* zj4 = (const float4*)(z + (bj * 16 + lr) * 32 + lg * 8);
    float4 zja = zj4[0], zjb = zj4[1];
    float zj[8] = {zja.x, zja.y, zja.z, zja.w, zjb.x, zjb.y, zjb.z, zjb.w};
    #pragma unroll
    for (int mt = 0; mt < 4; ++mt) {
      const int il = wm * 4 + mt;
      const float4* zi4 = (const float4*)(z + (bi * 8 + il) * 32 + lg * 8);
      float4 zia = zi4[0], zib = zi4[1];
      float zi[8] = {zia.x, zia.y, zia.z, zia.w, zib.x, zib.y, zib.z, zib.w};
      #pragma unroll
      for (int t = 0; t < 8; ++t) {
        float x = zi[t], y = zj[t];
        a0[mt][t] = (_Float16)fabsf(x - y);
        a1[mt][t] = (_Float16)(x * y);
      }
      #pragma unroll
      for (int t = 0; t < 8; ++t) {
        int k = 64 + lg * 8 + t;
        float v = (k < 72) ? (float)(k - 64 == il)
                : (k < 88) ? (float)(k - 72 == lr)
                           : (float)(k - 88 == il);
        a2[mt][t] = (_Float16)v;
      }
    }
    #pragma unroll
    for (int t = 0; t < 8; ++t) {
      int k = 96 + lg * 8 + t;
      a3[t] = (_Float16)(float)(k < 112 && (k - 96) == lr);
    }
  }

  // ---- staging (T14 split: LOAD early, WRITE after barrier) ----
  int4 l1v[2];
  int4 w2v[4];

  #define L1B_LOAD(c)                                                              \
    _Pragma("unroll") for (int s = 0; s < 2; ++s) {                                \
      int q = tid + 512 * s;                                                       \
      int nl = q >> 4, ch = q & 15;                                                \
      int ng = (c) * 64 + nl;                                                      \
      int4 v;                                                                      \
      if (ch < 8)       v = *(const int4*)(Wm + ng * 64 + ch * 8);                 \
      else if (ch == 8) v = *(const int4*)(RhT + (long)ng * NN + bi * 8);          \
      else if (ch == 9) v = *(const int4*)(ChT + (long)ng * NN + bj * 16);         \
      else if (ch == 10) v = *(const int4*)(ChT + (long)ng * NN + bj * 16 + 8);    \
      else if (ch == 11) v = *(const int4*)(R2hT + (long)ng * NN + bi * 8);        \
      else if (ch == 12) v = *(const int4*)(C2hT + (long)ng * NN + bj * 16);       \
      else if (ch == 13) v = *(const int4*)(C2hT + (long)ng * NN + bj * 16 + 8);   \
      else               v = (int4){0, 0, 0, 0};                                   \
      l1v[s] = v;                                                                  \
    }
  #define L1B_WRITE()                                                              \
    _Pragma("unroll") for (int s = 0; s < 2; ++s) {                                \
      int q = tid + 512 * s;                                                       \
      int nl = q >> 4, ch = q & 15;                                                \
      *(int4*)(l1b + nl * 256 + ((ch * 16) ^ ((nl & 7) << 4))) = l1v[s];           \
    }
  #define W2C_LOAD(c)                                                              \
    _Pragma("unroll") for (int s = 0; s < 4; ++s) {                                \
      int q = tid + 512 * s;                                                       \
      int n = q >> 3, ch = q & 7;                                                  \
      w2v[s] = *(const int4*)(W2t + n * 256 + (c) * 64 + ch * 8);                  \
    }
  #define W2C_WRITE()                                                              \
    _Pragma("unroll") for (int s = 0; s < 4; ++s) {                                \
      int q = tid + 512 * s;                                                       \
      int n = q >> 3, ch = q & 7;                                                  \
      *(int4*)(w2c + n * 128 + ((ch * 16) ^ ((n & 7) << 4))) = w2v[s];             \
    }

  // ---- prologue: stage chunk 0 ----
  L1B_LOAD(0); W2C_LOAD(0);
  L1B_WRITE(); W2C_WRITE();
  __syncthreads();

  f32x4 acc2[4][4];
  #pragma unroll
  for (int mt = 0; mt < 4; ++mt)
    #pragma unroll
    for (int nt = 0; nt < 4; ++nt) acc2[mt][nt] = (f32x4){0.f, 0.f, 0.f, 0.f};

  const int hl = wn * 16 + lr;    // wave's hidden col (chunk-local) for L1 A-operand
  for (int c = 0; c < 4; ++c) {
    // ---- layer-1 chunk (transposed): D[hidden 16 (wn slice)][pair 64 (wm band)] ----
    f32x4 acc1[4];
    #pragma unroll
    for (int mt = 0; mt < 4; ++mt) acc1[mt] = (f32x4){0.f, 0.f, 0.f, 0.f};
    #pragma unroll
    for (int ks = 0; ks < 4; ++ks) {
      f16x8 wf = *(const f16x8*)(l1b + hl * 256 + ((ks * 64 + lg * 16) ^ ((hl & 7) << 4)));
      #pragma unroll
      for (int mt = 0; mt < 4; ++mt) {
        f16x8 ft = (ks == 0) ? a0[mt] : (ks == 1) ? a1[mt] : (ks == 2) ? a2[mt] : a3;
        acc1[mt] = MFMA16(wf, ft, acc1[mt]);   // A = weights, B = features
      }
    }
    // pack (relu, f16): lane holds pair = wm*64+mt*16+lr, hidden = wn*16+4lg+r (r=0..3)
    #pragma unroll
    for (int mt = 0; mt < 4; ++mt) {
      f16x4 hv;
      #pragma unroll
      for (int r = 0; r < 4; ++r) {
        float v = acc1[mt][r];
        hv[r] = (_Float16)(v > 0.f ? v : 0.f);
      }
      int pair = wm * 64 + mt * 16 + lr;
      *(f16x4*)(h1c + pair * 128 + ((wn * 32 + lg * 8) ^ ((lr & 7) << 4))) = hv;
    }
    // issue next chunk's global loads (hidden under compute)
    if (c < 3) { L1B_LOAD(c + 1); W2C_LOAD(c + 1); }
    __syncthreads();                  // h1c visible; l1b[c] reads done
    if (c < 3) { L1B_WRITE(); }
    // ---- layer-2 partial: acc2 += h1[pairs][k-chunk] @ W2[k-chunk][cols] ----
    #pragma unroll
    for (int ks = 0; ks < 2; ++ks) {
      f16x8 af[4];
      #pragma unroll
      for (int mt = 0; mt < 4; ++mt) {
        int pair = wm * 64 + mt * 16 + lr;
        af[mt] = *(const f16x8*)(h1c + pair * 128 + ((ks * 64 + lg * 16) ^ ((lr & 7) << 4)));
      }
      #pragma unroll
      for (int nt = 0; nt < 4; ++nt) {
        int rw = wn * 64 + nt * 16 + lr;
        f16x8 bf = *(const f16x8*)(w2c + rw * 128 + ((ks * 64 + lg * 16) ^ ((rw & 7) << 4)));
        #pragma unroll
        for (int mt = 0; mt < 4; ++mt) acc2[mt][nt] = MFMA16(af[mt], bf, acc2[mt][nt]);
      }
    }
    __syncthreads();                  // w2c[c]/h1c reads done; l1b[c+1] visible
    if (c < 3) { W2C_WRITE(); }
  }

  // ---- epilogue: +b2, relu, dot W3 (fp32), cross-wave reduce, sigmoid ----
  #pragma unroll
  for (int mt = 0; mt < 4; ++mt) {
    #pragma unroll
    for (int r = 0; r < 4; ++r) {
      float sum = 0.f;
      #pragma unroll
      for (int nt = 0; nt < 4; ++nt) {
        float h2 = acc2[mt][nt][r] + b2v[nt];
        h2 = h2 > 0.f ? h2 : 0.f;
        sum += h2 * w3v[nt];
      }
      sum += __shfl_xor(sum, 1);
      sum += __shfl_xor(sum, 2);
      sum += __shfl_xor(sum, 4);
      sum += __shfl_xor(sum, 8);
      if (lr == 0) {
        int row = wm * 64 + mt * 16 + 4 * lg + r;
        red[row * 4 + wn] = sum;     // red aliases l1b (dead after last chunk)
      }
    }
  }
  __syncthreads();
  if (tid < 128) {
    int row = tid;
    float logit = red[row * 4 + 0] + red[row * 4 + 1] + red[row * 4 + 2] + red[row * 4 + 3] + b3v;
    float prob = 1.f / (1.f + expf(-logit));
    out[(bi * 8 + (row >> 4)) * NN + bj * 16 + (row & 15)] = prob;
  }
}

// ---------------- symmetrize in-place: out = 0.5*(P + P^T), zero diag ----------------
__global__ void sym_kernel(float* __restrict__ out) {
  int idx = blockIdx.x * 256 + threadIdx.x;
  if (idx >= NN * NN) return;
  int i = idx / NN, j = idx % NN;
  if (i < j) {
    float a = out[i * NN + j], b = out[j * NN + i];
    float v = 0.5f * (a + b);
    out[i * NN + j] = v;
    out[j * NN + i] = v;
  } else if (i == j) {
    out[idx] = 0.f;
  }
}

extern "C" void kernel_launch(void* const* d_in, const int* in_sizes, int n_in,
                              void* d_out, int out_size, void* d_ws, size_t ws_size,
                              hipStream_t stream) {
  const float* z   = (const float*)d_in[0];
  const float* lp  = (const float*)d_in[1];
  const float* hom = (const float*)d_in[2];
  const float* W1  = (const float*)d_in[3];
  const float* b1  = (const float*)d_in[4];
  const float* W2  = (const float*)d_in[5];
  const float* b2  = (const float*)d_in[6];
  const float* W3  = (const float*)d_in[7];
  const float* b3  = (const float*)d_in[8];
  float* out = (float*)d_out;

  char* ws = (char*)d_ws;
  _Float16* RhT  = (_Float16*)(ws);                  // 256*768*2 = 393216 each
  _Float16* ChT  = (_Float16*)(ws + 393216);
  _Float16* R2hT = (_Float16*)(ws + 786432);
  _Float16* C2hT = (_Float16*)(ws + 1179648);
  _Float16* Wm   = (_Float16*)(ws + 1572864);        // 256*64*2 = 32768
  _Float16* W2t  = (_Float16*)(ws + 1605632);        // 256*256*2 = 131072 -> end 1736704

  prep_all<<<368, 256, 0, stream>>>(z, lp, hom, W1, b1, W2, RhT, ChT, R2hT, C2hT, Wm, W2t);
  fused_mlp<<<dim3(96, 48), 512, 0, stream>>>(z, RhT, ChT, R2hT, C2hT, Wm, W2t, b2, W3, b3, out);
  sym_kernel<<<2304, 256, 0, stream>>>(out);
}